// Round 1
// baseline (87.443 us; speedup 1.0000x reference)
//
#include <hip/hip_runtime.h>
#include <float.h>
#include <math.h>

#define N 256
#define D 128
#define EPS_F 1e-4f
#define MARGIN_F 1.0f

// One block per row i. Computes d[i,:] into LDS, then per-thread-k the
// semihard loss term for pair (i,k), block-reduces to rowsum/rowcnt.
__global__ __launch_bounds__(N) void triplet_row_kernel(
    const float* __restrict__ E,      // [N, D] embeddings
    const int*   __restrict__ lab,    // [N] labels
    float* __restrict__ rowsum,       // [N] per-row sum of relu terms
    float* __restrict__ rowcnt)       // [N] per-row count of pos pairs
{
    __shared__ float ei[D];
    __shared__ float drow[N];
    __shared__ int   labs[N];
    __shared__ float red[8];

    const int i = blockIdx.x;
    const int k = threadIdx.x;

    // stage e_i (128 floats) and labels into LDS
    if (k < D / 4) {
        ((float4*)ei)[k] = ((const float4*)(E + (size_t)i * D))[k];
    }
    labs[k] = lab[k];
    __syncthreads();

    // d[i][k] = sqrt(max(||e_i - e_k||^2, EPS))  (i==k -> sqrt(EPS), matches ref)
    const float4* __restrict__ Ek = (const float4*)(E + (size_t)k * D);
    float s = 0.0f;
#pragma unroll
    for (int t = 0; t < D / 4; ++t) {
        float4 a = ((const float4*)ei)[t];
        float4 b = Ek[t];
        float dx = a.x - b.x, dy = a.y - b.y, dz = a.z - b.z, dw = a.w - b.w;
        s += dx * dx + dy * dy + dz * dz + dw * dw;
    }
    const float dik = sqrtf(fmaxf(s, EPS_F));
    drow[k] = dik;
    __syncthreads();

    // scan row: minS over semihard negatives {j in N_i : d_ij > d_ik},
    //           maxN over full negative set N_i = {label differs OR j==i}
    const int li = labs[i];
    float minS = FLT_MAX;
    float maxN = -FLT_MAX;
    for (int j = 0; j < N; ++j) {
        const float dij = drow[j];          // LDS broadcast (same addr all lanes)
        const bool neg = (labs[j] != li) || (j == i);
        if (neg) {
            maxN = fmaxf(maxN, dij);
            if (dij > dik) minS = fminf(minS, dij);
        }
    }

    const bool ispos = (labs[k] == li) && (k != i);
    const float chosen = (minS < FLT_MAX) ? minS : maxN;
    const float semi = dik - chosen;
    const float term = ispos ? fmaxf(semi + MARGIN_F, 0.0f) : 0.0f;
    const float cnt  = ispos ? 1.0f : 0.0f;

    // block reduction: 4 waves of 64
    float ts = term, cs = cnt;
    for (int off = 32; off > 0; off >>= 1) {
        ts += __shfl_down(ts, off);
        cs += __shfl_down(cs, off);
    }
    const int lane = k & 63;
    const int wid  = k >> 6;
    if (lane == 0) { red[wid] = ts; red[4 + wid] = cs; }
    __syncthreads();
    if (k == 0) {
        rowsum[i] = red[0] + red[1] + red[2] + red[3];
        rowcnt[i] = red[4] + red[5] + red[6] + red[7];
    }
}

__global__ __launch_bounds__(N) void triplet_final_kernel(
    const float* __restrict__ rowsum,
    const float* __restrict__ rowcnt,
    float* __restrict__ out)
{
    __shared__ float red[8];
    const int t = threadIdx.x;
    float s = rowsum[t];
    float c = rowcnt[t];
    for (int off = 32; off > 0; off >>= 1) {
        s += __shfl_down(s, off);
        c += __shfl_down(c, off);
    }
    const int lane = t & 63;
    const int wid  = t >> 6;
    if (lane == 0) { red[wid] = s; red[4 + wid] = c; }
    __syncthreads();
    if (t == 0) {
        out[0] = (red[0] + red[1] + red[2] + red[3]) /
                 (red[4] + red[5] + red[6] + red[7]);
    }
}

extern "C" void kernel_launch(void* const* d_in, const int* in_sizes, int n_in,
                              void* d_out, int out_size, void* d_ws, size_t ws_size,
                              hipStream_t stream) {
    const float* E   = (const float*)d_in[0];   // embeddings [256,128] fp32
    const int*   lab = (const int*)d_in[1];     // labels [256] int
    float* out = (float*)d_out;                 // scalar fp32

    float* rowsum = (float*)d_ws;               // [N]
    float* rowcnt = rowsum + N;                 // [N]

    triplet_row_kernel<<<N, N, 0, stream>>>(E, lab, rowsum, rowcnt);
    triplet_final_kernel<<<1, N, 0, stream>>>(rowsum, rowcnt, out);
}

// Round 2
// 73.940 us; speedup vs baseline: 1.1826x; 1.1826x over previous
//
#include <hip/hip_runtime.h>
#include <float.h>
#include <math.h>

#define N 256
#define D 128
#define EPS_F 1e-4f
#define MARGIN_F 1.0f

// One block per row i. Computes d[i,:] into LDS, scans for semihard negatives,
// block-reduces (sum of relu terms, global pos count), atomicAdds sum/cnt into out.
// Global cnt = sum_k (n_{lab[k]} - 1) is identical in every block, so
// sum_blocks (rowsum_i / cnt) == total/cnt exactly as the reference computes.
__global__ __launch_bounds__(N) void triplet_fused_kernel(
    const float* __restrict__ E,      // [N, D] embeddings
    const int*   __restrict__ lab,    // [N] labels
    float* __restrict__ out)          // scalar (pre-zeroed by memset node)
{
    __shared__ __align__(16) float ei[D];
    __shared__ __align__(16) float drow[N];
    __shared__ __align__(16) int   labs[N];
    __shared__ float red[8];

    const int i = blockIdx.x;
    const int k = threadIdx.x;

    if (k < D / 4) {
        ((float4*)ei)[k] = ((const float4*)(E + (size_t)i * D))[k];
    }
    labs[k] = lab[k];
    __syncthreads();

    // d[i][k] = sqrt(max(||e_i - e_k||^2, EPS))  (i==k -> sqrt(EPS))
    const float4* __restrict__ Ek = (const float4*)(E + (size_t)k * D);
    float s = 0.0f;
#pragma unroll
    for (int t = 0; t < D / 4; ++t) {
        float4 a = ((const float4*)ei)[t];
        float4 b = Ek[t];
        float dx = a.x - b.x, dy = a.y - b.y, dz = a.z - b.z, dw = a.w - b.w;
        s += dx * dx + dy * dy + dz * dz + dw * dw;
    }
    const float dik = sqrtf(fmaxf(s, EPS_F));
    drow[k] = dik;
    __syncthreads();

    const int li = labs[i];   // row label
    const int lk = labs[k];   // this thread's column label

    // Scan row in chunks of 4 via LDS b128 reads:
    //   minS over {j : neg(j) && d_ij > d_ik}, maxN over neg set,
    //   matches = #{j : lab[j]==lab[k]} (for the global pos count).
    float minS = FLT_MAX;
    float maxN = -FLT_MAX;
    int   matches = 0;
#pragma unroll 4
    for (int jj = 0; jj < N / 4; ++jj) {
        const float4 d4 = ((const float4*)drow)[jj];
        const int4   l4 = ((const int4*)labs)[jj];
        const int j0 = jj * 4;
        {
            const bool nz = (l4.x != li) || (j0 + 0 == i);
            maxN = fmaxf(maxN, nz ? d4.x : -FLT_MAX);
            minS = fminf(minS, (nz && d4.x > dik) ? d4.x : FLT_MAX);
            matches += (l4.x == lk);
        }
        {
            const bool nz = (l4.y != li) || (j0 + 1 == i);
            maxN = fmaxf(maxN, nz ? d4.y : -FLT_MAX);
            minS = fminf(minS, (nz && d4.y > dik) ? d4.y : FLT_MAX);
            matches += (l4.y == lk);
        }
        {
            const bool nz = (l4.z != li) || (j0 + 2 == i);
            maxN = fmaxf(maxN, nz ? d4.z : -FLT_MAX);
            minS = fminf(minS, (nz && d4.z > dik) ? d4.z : FLT_MAX);
            matches += (l4.z == lk);
        }
        {
            const bool nz = (l4.w != li) || (j0 + 3 == i);
            maxN = fmaxf(maxN, nz ? d4.w : -FLT_MAX);
            minS = fminf(minS, (nz && d4.w > dik) ? d4.w : FLT_MAX);
            matches += (l4.w == lk);
        }
    }

    const bool ispos = (lk == li) && (k != i);
    const float chosen = (minS < FLT_MAX) ? minS : maxN;
    const float term = ispos ? fmaxf(dik - chosen + MARGIN_F, 0.0f) : 0.0f;
    const float cntk = (float)(matches - 1);   // n_{lab[k]} - 1

    // block reduction: 4 waves of 64
    float ts = term, cs = cntk;
    for (int off = 32; off > 0; off >>= 1) {
        ts += __shfl_down(ts, off);
        cs += __shfl_down(cs, off);
    }
    const int lane = k & 63;
    const int wid  = k >> 6;
    if (lane == 0) { red[wid] = ts; red[4 + wid] = cs; }
    __syncthreads();
    if (k == 0) {
        const float blocksum = red[0] + red[1] + red[2] + red[3];
        const float cnt      = red[4] + red[5] + red[6] + red[7]; // global pos count
        atomicAdd(out, blocksum / cnt);
    }
}

extern "C" void kernel_launch(void* const* d_in, const int* in_sizes, int n_in,
                              void* d_out, int out_size, void* d_ws, size_t ws_size,
                              hipStream_t stream) {
    const float* E   = (const float*)d_in[0];   // embeddings [256,128] fp32
    const int*   lab = (const int*)d_in[1];     // labels [256] int
    float* out = (float*)d_out;                 // scalar fp32

    // d_out is poisoned to 0xAA before every timed replay; zero it (capture-safe).
    hipMemsetAsync(out, 0, sizeof(float) * out_size, stream);
    triplet_fused_kernel<<<N, N, 0, stream>>>(E, lab, out);
}